// Round 5
// baseline (770.726 us; speedup 1.0000x reference)
//
#include <hip/hip_runtime.h>
#include <hip/hip_bf16.h>
#include <math.h>

#define Ddim 1024
#define Mrows 4096
#define Ncols 8192
#define BM 128
#define BN 256
#define BK 32
#define CS 64                          // lse partials per row (128 cols each)
#define CT (Ncols / BN)                // 32 col-tiles
#define RT (Mrows / BM)                // 32 row-tiles
#define KITERS (Ddim / BK)             // 32
#define SCALE 20.0f                    // 1/TEMPERATURE
#define ARR_ELEMS (Mrows * Ddim)       // 4194304 per input array

typedef __bf16 bf16_t;
typedef __bf16 bf16x8 __attribute__((ext_vector_type(8)));
typedef float f32x4 __attribute__((ext_vector_type(4)));

// global->LDS DMA, 16B per lane, lds dest = wave-uniform base + lane*16
#define LOAD16_TO_LDS(g, l)                                                  \
  __builtin_amdgcn_global_load_lds(                                          \
      (const __attribute__((address_space(1))) void*)(g),                    \
      (__attribute__((address_space(3))) void*)(l), 16, 0, 0)

// ---------------------------------------------------------------------------
// Kernel 0: f32 -> bf16 conversion pre-pass (one-shot, memory-bound)
// ---------------------------------------------------------------------------
__global__ __launch_bounds__(256) void cvt_kernel(
    const float* __restrict__ o, const float* __restrict__ pos,
    const float* __restrict__ neg, bf16_t* __restrict__ ob,
    bf16_t* __restrict__ pb, bf16_t* __restrict__ nb)
{
  const int idx = blockIdx.x * 256 + threadIdx.x;   // 0 .. 3*ARR/8-1
  const int seg = idx >> 19;                        // ARR_ELEMS/8 = 2^19
  const int off = idx & ((1 << 19) - 1);
  const float* src = (seg == 0) ? o : (seg == 1) ? pos : neg;
  bf16_t* dst = (seg == 0) ? ob : (seg == 1) ? pb : nb;
  const float4 v0 = *(const float4*)(src + (size_t)off * 8);
  const float4 v1 = *(const float4*)(src + (size_t)off * 8 + 4);
  bf16x8 r = {(bf16_t)v0.x, (bf16_t)v0.y, (bf16_t)v0.z, (bf16_t)v0.w,
              (bf16_t)v1.x, (bf16_t)v1.y, (bf16_t)v1.z, (bf16_t)v1.w};
  *(bf16x8*)(dst + (size_t)off * 8) = r;
}

// ---------------------------------------------------------------------------
// Kernel 1: bf16 GEMM (o · emb^T) + partial LSE + diagonal-block extraction.
// 128x256 block, 2x2 wave grid, each wave 64x128 (4 A-frags x 8 B-frags =
// 32 MFMA per 12 ds_read_b128 -> 43.7 kFLOP/read; LDS floor ~= MFMA floor).
// Double-buffered LDS, global_load_lds DMA, XOR source-swizzle (0 conflicts).
// Blocks with ct == rt>>1 also dump the 8 diagonal 16x16 sub-blocks straight
// from the accumulators (replaces the old block_dots kernel).
// ---------------------------------------------------------------------------
__global__ __launch_bounds__(256, 2) void gemm_lse_kernel(
    const bf16_t* __restrict__ ob, const bf16_t* __restrict__ pb,
    const bf16_t* __restrict__ nb, float* __restrict__ pm,
    float* __restrict__ pl, float* __restrict__ blocks_raw)
{
  __shared__ bf16_t As[2][BM * BK];   // 2 x 8 KB
  __shared__ bf16_t Bs[2][BN * BK];   // 2 x 16 KB

  const int bid = blockIdx.x;
  const int rt = bid >> 5;        // 0..31
  const int ct = bid & 31;        // 0..31
  const int row0 = rt * BM;
  const bf16_t* Eb = (ct < 16) ? (pb + (size_t)ct * BN * Ddim)
                               : (nb + (size_t)(ct - 16) * BN * Ddim);

  const int t = threadIdx.x;
  const int wave = t >> 6;
  const int wr = wave & 1;        // row half (64 rows)
  const int wc = wave >> 1;       // col half (128 cols)
  const int lane = t & 63;
  const int quad = lane >> 4;
  const int l16 = lane & 15;
  const int koff = ((quad ^ ((l16 >> 1) & 3)) << 3);   // fragment chunk offset
  const int lr4 = lane >> 2;                            // staging row-in-16
  const int cstg = lane & 3;                            // staging chunk id

  f32x4 acc[4][8];
#pragma unroll
  for (int a = 0; a < 4; ++a)
#pragma unroll
    for (int b = 0; b < 8; ++b) acc[a][b] = (f32x4){0.f, 0.f, 0.f, 0.f};

  // prologue: stage tile 0 into buffer 0
#pragma unroll
  for (int cl = 0; cl < 2; ++cl) {
    const int r = wave * 32 + cl * 16 + lr4;
    const int gc = cstg ^ ((r >> 1) & 3);
    LOAD16_TO_LDS(ob + (size_t)(row0 + r) * Ddim + gc * 8,
                  &As[0][(wave * 32 + cl * 16) * BK]);
  }
#pragma unroll
  for (int cl = 0; cl < 4; ++cl) {
    const int r = wave * 64 + cl * 16 + lr4;
    const int gc = cstg ^ ((r >> 1) & 3);
    LOAD16_TO_LDS(Eb + (size_t)r * Ddim + gc * 8,
                  &Bs[0][(wave * 64 + cl * 16) * BK]);
  }

  int p = 0;
  for (int kc = 0; kc < KITERS; ++kc) {
    __syncthreads();   // drains DMA for buf p; protects buf p^1 reuse
    if (kc + 1 < KITERS) {
      const int k0 = (kc + 1) * BK;
#pragma unroll
      for (int cl = 0; cl < 2; ++cl) {
        const int r = wave * 32 + cl * 16 + lr4;
        const int gc = cstg ^ ((r >> 1) & 3);
        LOAD16_TO_LDS(ob + (size_t)(row0 + r) * Ddim + k0 + gc * 8,
                      &As[p ^ 1][(wave * 32 + cl * 16) * BK]);
      }
#pragma unroll
      for (int cl = 0; cl < 4; ++cl) {
        const int r = wave * 64 + cl * 16 + lr4;
        const int gc = cstg ^ ((r >> 1) & 3);
        LOAD16_TO_LDS(Eb + (size_t)r * Ddim + k0 + gc * 8,
                      &Bs[p ^ 1][(wave * 64 + cl * 16) * BK]);
      }
    }

    bf16x8 af[4];
#pragma unroll
    for (int fm = 0; fm < 4; ++fm)
      af[fm] = *(const bf16x8*)(&As[p][(wr * 64 + fm * 16 + l16) * BK + koff]);
#pragma unroll
    for (int fn = 0; fn < 8; ++fn) {
      const bf16x8 bf = *(const bf16x8*)(&Bs[p][(wc * 128 + fn * 16 + l16) * BK + koff]);
#pragma unroll
      for (int fm = 0; fm < 4; ++fm)
        acc[fm][fn] = __builtin_amdgcn_mfma_f32_16x16x32_bf16(af[fm], bf, acc[fm][fn], 0, 0, 0);
    }
    p ^= 1;
  }

  // epilogue A: per-row (m, l) over this wave's 128 cols.
  // C/D: col = wc*128 + fn*16 + l16, row = wr*64 + fm*16 + quad*4 + r
  const int csp = ct * 2 + wc;     // partial-lse column index (0..63)
#pragma unroll
  for (int fm = 0; fm < 4; ++fm) {
#pragma unroll
    for (int r = 0; r < 4; ++r) {
      float s[8];
#pragma unroll
      for (int fn = 0; fn < 8; ++fn) s[fn] = acc[fm][fn][r] * SCALE;
      float m = s[0];
#pragma unroll
      for (int fn = 1; fn < 8; ++fn) m = fmaxf(m, s[fn]);
#pragma unroll
      for (int off = 1; off <= 8; off <<= 1)
        m = fmaxf(m, __shfl_xor(m, off, 64));   // row max over l16 group
      float l = 0.f;
#pragma unroll
      for (int fn = 0; fn < 8; ++fn) l += __expf(s[fn] - m);
#pragma unroll
      for (int off = 1; off <= 8; off <<= 1)
        l += __shfl_xor(l, off, 64);
      if (l16 == 0) {
        const int rg = row0 + wr * 64 + fm * 16 + quad * 4 + r;
        pm[(size_t)rg * CS + csp] = m;
        pl[(size_t)rg * CS + csp] = l;
      }
    }
  }

  // epilogue B: diagonal 16x16 sub-blocks. Block (rt, ct=rt>>1), wave half
  // wc == rt&1 holds sub-block d = wr*4 + fm at fn == d.
  if (ct == (rt >> 1) && wc == (rt & 1)) {
#pragma unroll
    for (int fm = 0; fm < 4; ++fm) {
      const int d = wr * 4 + fm;
      const int b = rt * 8 + d;
#pragma unroll
      for (int r = 0; r < 4; ++r)
        blocks_raw[b * 256 + (quad * 4 + r) * 16 + l16] = acc[fm][d][r] * SCALE;
    }
  }
}

// ---------------------------------------------------------------------------
// Kernel 2: fused lse-combine + lane-parallel JV LAP + atomic loss.
// Single wave per block, no barriers; u[] in row-lane registers.
// ---------------------------------------------------------------------------
__global__ __launch_bounds__(64) void hungarian_kernel(
    const float* __restrict__ blocks_raw, const float* __restrict__ pm,
    const float* __restrict__ pl, float* __restrict__ out)
{
  const int b = blockIdx.x;
  const int L = threadIdx.x;
  __shared__ float C[16][16];
  __shared__ float lse_s[16];

  for (int e = L; e < 256; e += 64)
    C[e >> 4][e & 15] = blocks_raw[b * 256 + e];

  // combine 64 partial (m,l) per row -> lse. lane = r + 16*g handles
  // partial chunk [g*16, g*16+16) of row r, then merges across g.
  {
    const int r = L & 15, g = L >> 4;
    const size_t base = (size_t)(b * 16 + r) * CS + g * 16;
    float m = -INFINITY, l = 0.f;
#pragma unroll
    for (int k = 0; k < 16; ++k) {
      const float m2 = pm[base + k];
      const float l2 = pl[base + k];
      const float M = fmaxf(m, m2);
      l = l * __expf(m - M) + l2 * __expf(m2 - M);
      m = M;
    }
#pragma unroll
    for (int off = 16; off <= 32; off <<= 1) {
      const float m2 = __shfl_xor(m, off, 64);
      const float l2 = __shfl_xor(l, off, 64);
      const float M = fmaxf(m, m2);
      l = l * __expf(m - M) + l2 * __expf(m2 - M);
      m = M;
    }
    if (g == 0) lse_s[r] = m + logf(l);
  }

  const float INF = 3.0e38f;
  float vj = 0.f, u_reg = 0.f;
  int pj = 0;
  float minv = INF;
  int wayj = 0;
  bool usedj = false, on_tree = false;

  for (int i = 1; i <= 16; ++i) {
    if (L == 0) pj = i;          // p[0] = current row
    minv = INF; wayj = 0; usedj = false; on_tree = false;
    int j0 = 0;
    while (true) {
      usedj = usedj || (L == j0);
      const int i0 = __shfl(pj, j0, 64);        // row entering the tree
      if (L == i0) on_tree = true;
      const float ui0 = __shfl(u_reg, i0, 64);
      if (L >= 1 && L <= 16 && !usedj) {
        const float cur = -C[i0 - 1][L - 1] - ui0 - vj;
        if (cur < minv) { minv = cur; wayj = j0; }
      }
      float cand = (L >= 1 && L <= 16 && !usedj) ? minv : INF;
      int idx = L;
#pragma unroll
      for (int off = 16; off > 0; off >>= 1) {
        const float ov = __shfl_xor(cand, off, 32);
        const int oi = __shfl_xor(idx, off, 32);
        if (ov < cand || (ov == cand && oi < idx)) { cand = ov; idx = oi; }
      }
      const float delta = cand;                  // valid in lanes 0..31
      const int j1 = __builtin_amdgcn_readfirstlane(idx);  // uniform
      if (L >= 1 && L <= 16) {
        if (usedj) vj -= delta; else minv -= delta;
        if (on_tree) u_reg += delta;
      }
      j0 = j1;
      const int pj0 = __shfl(pj, j0, 64);
      if (pj0 == 0) break;
    }
    // augment
    while (j0 != 0) {
      const int j1a = __shfl(wayj, j0, 64);
      const int pjn = __shfl(pj, j1a, 64);
      if (L == j0) pj = pjn;
      j0 = j1a;
    }
  }

  float loss = 0.f;
  if (L >= 1 && L <= 16) loss = lse_s[pj - 1] - C[pj - 1][L - 1];
#pragma unroll
  for (int off = 32; off > 0; off >>= 1) loss += __shfl_down(loss, off, 64);
  if (L == 0) atomicAdd(out, loss * (1.0f / 4096.0f));
}

extern "C" void kernel_launch(void* const* d_in, const int* in_sizes, int n_in,
                              void* d_out, int out_size, void* d_ws, size_t ws_size,
                              hipStream_t stream) {
  const float* o   = (const float*)d_in[0];  // (256,16,1024) f32
  const float* pos = (const float*)d_in[1];
  const float* neg = (const float*)d_in[2];
  float* out = (float*)d_out;

  float* ws = (float*)d_ws;
  float* pm         = ws;                       // 4096*64 = 1 MB
  float* pl         = pm + (size_t)4096 * CS;   // 4096*64 = 1 MB
  float* blocks_raw = pl + (size_t)4096 * CS;   // 256*256
  bf16_t* ob = (bf16_t*)(blocks_raw + 65536);   // 3 x 4194304 bf16
  bf16_t* pb = ob + (size_t)ARR_ELEMS;
  bf16_t* nb = pb + (size_t)ARR_ELEMS;

  hipMemsetAsync(out, 0, sizeof(float), stream);
  cvt_kernel<<<3 * ARR_ELEMS / 8 / 256, 256, 0, stream>>>(o, pos, neg, ob, pb, nb);
  gemm_lse_kernel<<<RT * CT, 256, 0, stream>>>(ob, pb, nb, pm, pl, blocks_raw);
  hungarian_kernel<<<256, 64, 0, stream>>>(blocks_raw, pm, pl, out);
}

// Round 6
// 234.869 us; speedup vs baseline: 3.2815x; 3.2815x over previous
//
#include <hip/hip_runtime.h>
#include <hip/hip_bf16.h>
#include <math.h>

#define Ddim 1024
#define Mrows 4096
#define Ncols 8192
#define BM 128
#define BN 256
#define BK 32
#define CS 64                          // lse partials per row (128 cols each)
#define CT (Ncols / BN)                // 32 col-tiles
#define RT (Mrows / BM)                // 32 row-tiles
#define KITERS (Ddim / BK)             // 32
#define SCALE 20.0f                    // 1/TEMPERATURE
#define ARR_ELEMS (Mrows * Ddim)       // 4194304 per input array

typedef __bf16 bf16_t;
typedef __bf16 bf16x8 __attribute__((ext_vector_type(8)));
typedef float f32x4 __attribute__((ext_vector_type(4)));

// global->LDS DMA, 16B per lane, lds dest = wave-uniform base + lane*16
#define LOAD16_TO_LDS(g, l)                                                  \
  __builtin_amdgcn_global_load_lds(                                          \
      (const __attribute__((address_space(1))) void*)(g),                    \
      (__attribute__((address_space(3))) void*)(l), 16, 0, 0)

// ---------------------------------------------------------------------------
// Kernel 0: f32 -> bf16 conversion pre-pass (one-shot, memory-bound)
// ---------------------------------------------------------------------------
__global__ __launch_bounds__(256) void cvt_kernel(
    const float* __restrict__ o, const float* __restrict__ pos,
    const float* __restrict__ neg, bf16_t* __restrict__ ob,
    bf16_t* __restrict__ pb, bf16_t* __restrict__ nb)
{
  const int idx = blockIdx.x * 256 + threadIdx.x;   // 0 .. 3*ARR/8-1
  const int seg = idx >> 19;                        // ARR_ELEMS/8 = 2^19
  const int off = idx & ((1 << 19) - 1);
  const float* src = (seg == 0) ? o : (seg == 1) ? pos : neg;
  bf16_t* dst = (seg == 0) ? ob : (seg == 1) ? pb : nb;
  const float4 v0 = *(const float4*)(src + (size_t)off * 8);
  const float4 v1 = *(const float4*)(src + (size_t)off * 8 + 4);
  bf16x8 r = {(bf16_t)v0.x, (bf16_t)v0.y, (bf16_t)v0.z, (bf16_t)v0.w,
              (bf16_t)v1.x, (bf16_t)v1.y, (bf16_t)v1.z, (bf16_t)v1.w};
  *(bf16x8*)(dst + (size_t)off * 8) = r;
}

// ---------------------------------------------------------------------------
// Kernel 1: bf16 GEMM (o · emb^T) + partial LSE + diagonal-block extraction.
// 128x256 block, 2x2 wave grid, each wave 64x128 (4 A-frags x 8 B-frags =
// 32 MFMA per 12 ds_read_b128). Double-buffered LDS + global_load_lds DMA +
// XOR source-swizzle (0 bank conflicts).
// NOTE: accumulator array must ONLY be indexed with compile-time constants —
// R5's acc[fm][d] (runtime d) demoted the whole array to scratch (4.3 GB of
// spill writes per dispatch, 7x regression).
// ---------------------------------------------------------------------------
__global__ __launch_bounds__(256, 2) void gemm_lse_kernel(
    const bf16_t* __restrict__ ob, const bf16_t* __restrict__ pb,
    const bf16_t* __restrict__ nb, float* __restrict__ pm,
    float* __restrict__ pl, float* __restrict__ blocks_raw)
{
  __shared__ bf16_t As[2][BM * BK];   // 2 x 8 KB
  __shared__ bf16_t Bs[2][BN * BK];   // 2 x 16 KB

  const int bid = blockIdx.x;
  const int rt = bid >> 5;        // 0..31
  const int ct = bid & 31;        // 0..31
  const int row0 = rt * BM;
  const bf16_t* Eb = (ct < 16) ? (pb + (size_t)ct * BN * Ddim)
                               : (nb + (size_t)(ct - 16) * BN * Ddim);

  const int t = threadIdx.x;
  const int wave = t >> 6;
  const int wr = wave & 1;        // row half (64 rows)
  const int wc = wave >> 1;       // col half (128 cols)
  const int lane = t & 63;
  const int quad = lane >> 4;
  const int l16 = lane & 15;
  const int koff = ((quad ^ ((l16 >> 1) & 3)) << 3);   // fragment chunk offset
  const int lr4 = lane >> 2;                            // staging row-in-16
  const int cstg = lane & 3;                            // staging chunk id

  f32x4 acc[4][8];
#pragma unroll
  for (int a = 0; a < 4; ++a)
#pragma unroll
    for (int b = 0; b < 8; ++b) acc[a][b] = (f32x4){0.f, 0.f, 0.f, 0.f};

  // prologue: stage tile 0 into buffer 0
#pragma unroll
  for (int cl = 0; cl < 2; ++cl) {
    const int r = wave * 32 + cl * 16 + lr4;
    const int gc = cstg ^ ((r >> 1) & 3);
    LOAD16_TO_LDS(ob + (size_t)(row0 + r) * Ddim + gc * 8,
                  &As[0][(wave * 32 + cl * 16) * BK]);
  }
#pragma unroll
  for (int cl = 0; cl < 4; ++cl) {
    const int r = wave * 64 + cl * 16 + lr4;
    const int gc = cstg ^ ((r >> 1) & 3);
    LOAD16_TO_LDS(Eb + (size_t)r * Ddim + gc * 8,
                  &Bs[0][(wave * 64 + cl * 16) * BK]);
  }

  int p = 0;
  for (int kc = 0; kc < KITERS; ++kc) {
    __syncthreads();   // drains DMA for buf p; protects buf p^1 reuse
    if (kc + 1 < KITERS) {
      const int k0 = (kc + 1) * BK;
#pragma unroll
      for (int cl = 0; cl < 2; ++cl) {
        const int r = wave * 32 + cl * 16 + lr4;
        const int gc = cstg ^ ((r >> 1) & 3);
        LOAD16_TO_LDS(ob + (size_t)(row0 + r) * Ddim + k0 + gc * 8,
                      &As[p ^ 1][(wave * 32 + cl * 16) * BK]);
      }
#pragma unroll
      for (int cl = 0; cl < 4; ++cl) {
        const int r = wave * 64 + cl * 16 + lr4;
        const int gc = cstg ^ ((r >> 1) & 3);
        LOAD16_TO_LDS(Eb + (size_t)r * Ddim + k0 + gc * 8,
                      &Bs[p ^ 1][(wave * 64 + cl * 16) * BK]);
      }
    }

    bf16x8 af[4];
#pragma unroll
    for (int fm = 0; fm < 4; ++fm)
      af[fm] = *(const bf16x8*)(&As[p][(wr * 64 + fm * 16 + l16) * BK + koff]);
#pragma unroll
    for (int fn = 0; fn < 8; ++fn) {
      const bf16x8 bf = *(const bf16x8*)(&Bs[p][(wc * 128 + fn * 16 + l16) * BK + koff]);
#pragma unroll
      for (int fm = 0; fm < 4; ++fm)
        acc[fm][fn] = __builtin_amdgcn_mfma_f32_16x16x32_bf16(af[fm], bf, acc[fm][fn], 0, 0, 0);
    }
    p ^= 1;
  }

  // epilogue A: per-row (m, l) over this wave's 128 cols.
  // C/D: col = wc*128 + fn*16 + l16, row = wr*64 + fm*16 + quad*4 + r
  const int csp = ct * 2 + wc;     // partial-lse column index (0..63)
#pragma unroll
  for (int fm = 0; fm < 4; ++fm) {
#pragma unroll
    for (int r = 0; r < 4; ++r) {
      float s[8];
#pragma unroll
      for (int fn = 0; fn < 8; ++fn) s[fn] = acc[fm][fn][r] * SCALE;
      float m = s[0];
#pragma unroll
      for (int fn = 1; fn < 8; ++fn) m = fmaxf(m, s[fn]);
#pragma unroll
      for (int off = 1; off <= 8; off <<= 1)
        m = fmaxf(m, __shfl_xor(m, off, 64));   // row max over l16 group
      float l = 0.f;
#pragma unroll
      for (int fn = 0; fn < 8; ++fn) l += __expf(s[fn] - m);
#pragma unroll
      for (int off = 1; off <= 8; off <<= 1)
        l += __shfl_xor(l, off, 64);
      if (l16 == 0) {
        const int rg = row0 + wr * 64 + fm * 16 + quad * 4 + r;
        pm[(size_t)rg * CS + csp] = m;
        pl[(size_t)rg * CS + csp] = l;
      }
    }
  }

  // epilogue B: diagonal 16x16 sub-blocks, via constant-index unroll with a
  // runtime fn==d guard (keeps acc in AGPRs — no dynamic register indexing).
  if (ct == (rt >> 1) && wc == (rt & 1)) {
#pragma unroll
    for (int fm = 0; fm < 4; ++fm) {
      const int d = wr * 4 + fm;       // runtime (wr), but acc idx below is const
      const int b = rt * 8 + d;
#pragma unroll
      for (int fn = 0; fn < 8; ++fn) {
        if (fn == d) {
#pragma unroll
          for (int r = 0; r < 4; ++r)
            blocks_raw[b * 256 + (quad * 4 + r) * 16 + l16] = acc[fm][fn][r] * SCALE;
        }
      }
    }
  }
}

// ---------------------------------------------------------------------------
// Kernel 2: fused lse-combine + lane-parallel JV LAP + atomic loss.
// Single wave per block, no barriers; u[] in row-lane registers.
// ---------------------------------------------------------------------------
__global__ __launch_bounds__(64) void hungarian_kernel(
    const float* __restrict__ blocks_raw, const float* __restrict__ pm,
    const float* __restrict__ pl, float* __restrict__ out)
{
  const int b = blockIdx.x;
  const int L = threadIdx.x;
  __shared__ float C[16][16];
  __shared__ float lse_s[16];

  for (int e = L; e < 256; e += 64)
    C[e >> 4][e & 15] = blocks_raw[b * 256 + e];

  // combine 64 partial (m,l) per row -> lse. lane = r + 16*g handles
  // partial chunk [g*16, g*16+16) of row r, then merges across g.
  {
    const int r = L & 15, g = L >> 4;
    const size_t base = (size_t)(b * 16 + r) * CS + g * 16;
    float m = -INFINITY, l = 0.f;
#pragma unroll
    for (int k = 0; k < 16; ++k) {
      const float m2 = pm[base + k];
      const float l2 = pl[base + k];
      const float M = fmaxf(m, m2);
      l = l * __expf(m - M) + l2 * __expf(m2 - M);
      m = M;
    }
#pragma unroll
    for (int off = 16; off <= 32; off <<= 1) {
      const float m2 = __shfl_xor(m, off, 64);
      const float l2 = __shfl_xor(l, off, 64);
      const float M = fmaxf(m, m2);
      l = l * __expf(m - M) + l2 * __expf(m2 - M);
      m = M;
    }
    if (g == 0) lse_s[r] = m + logf(l);
  }

  const float INF = 3.0e38f;
  float vj = 0.f, u_reg = 0.f;
  int pj = 0;
  float minv = INF;
  int wayj = 0;
  bool usedj = false, on_tree = false;

  for (int i = 1; i <= 16; ++i) {
    if (L == 0) pj = i;          // p[0] = current row
    minv = INF; wayj = 0; usedj = false; on_tree = false;
    int j0 = 0;
    while (true) {
      usedj = usedj || (L == j0);
      const int i0 = __shfl(pj, j0, 64);        // row entering the tree
      if (L == i0) on_tree = true;
      const float ui0 = __shfl(u_reg, i0, 64);
      if (L >= 1 && L <= 16 && !usedj) {
        const float cur = -C[i0 - 1][L - 1] - ui0 - vj;
        if (cur < minv) { minv = cur; wayj = j0; }
      }
      float cand = (L >= 1 && L <= 16 && !usedj) ? minv : INF;
      int idx = L;
#pragma unroll
      for (int off = 16; off > 0; off >>= 1) {
        const float ov = __shfl_xor(cand, off, 32);
        const int oi = __shfl_xor(idx, off, 32);
        if (ov < cand || (ov == cand && oi < idx)) { cand = ov; idx = oi; }
      }
      const float delta = cand;                  // valid in lanes 0..31
      const int j1 = __builtin_amdgcn_readfirstlane(idx);  // uniform
      if (L >= 1 && L <= 16) {
        if (usedj) vj -= delta; else minv -= delta;
        if (on_tree) u_reg += delta;
      }
      j0 = j1;
      const int pj0 = __shfl(pj, j0, 64);
      if (pj0 == 0) break;
    }
    // augment
    while (j0 != 0) {
      const int j1a = __shfl(wayj, j0, 64);
      const int pjn = __shfl(pj, j1a, 64);
      if (L == j0) pj = pjn;
      j0 = j1a;
    }
  }

  float loss = 0.f;
  if (L >= 1 && L <= 16) loss = lse_s[pj - 1] - C[pj - 1][L - 1];
#pragma unroll
  for (int off = 32; off > 0; off >>= 1) loss += __shfl_down(loss, off, 64);
  if (L == 0) atomicAdd(out, loss * (1.0f / 4096.0f));
}

extern "C" void kernel_launch(void* const* d_in, const int* in_sizes, int n_in,
                              void* d_out, int out_size, void* d_ws, size_t ws_size,
                              hipStream_t stream) {
  const float* o   = (const float*)d_in[0];  // (256,16,1024) f32
  const float* pos = (const float*)d_in[1];
  const float* neg = (const float*)d_in[2];
  float* out = (float*)d_out;

  float* ws = (float*)d_ws;
  float* pm         = ws;                       // 4096*64 = 1 MB
  float* pl         = pm + (size_t)4096 * CS;   // 4096*64 = 1 MB
  float* blocks_raw = pl + (size_t)4096 * CS;   // 256*256
  bf16_t* ob = (bf16_t*)(blocks_raw + 65536);   // 3 x 4194304 bf16
  bf16_t* pb = ob + (size_t)ARR_ELEMS;
  bf16_t* nb = pb + (size_t)ARR_ELEMS;

  hipMemsetAsync(out, 0, sizeof(float), stream);
  cvt_kernel<<<3 * ARR_ELEMS / 8 / 256, 256, 0, stream>>>(o, pos, neg, ob, pb, nb);
  gemm_lse_kernel<<<RT * CT, 256, 0, stream>>>(ob, pb, nb, pm, pl, blocks_raw);
  hungarian_kernel<<<256, 64, 0, stream>>>(blocks_raw, pm, pl, out);
}

// Round 7
// 225.521 us; speedup vs baseline: 3.4175x; 1.0415x over previous
//
#include <hip/hip_runtime.h>
#include <hip/hip_bf16.h>
#include <math.h>

#define Ddim 1024
#define Mrows 4096
#define Ncols 8192
#define BM 128
#define BN 128
#define BK 32
#define NCS 64                         // 64 col-split blocks of 128 cols
#define CS 128                         // lse partials per row (64 cols each)
#define RT (Mrows / BM)                // 32
#define KITERS (Ddim / BK)             // 32
#define SCALE 20.0f                    // 1/TEMPERATURE
#define ARR_ELEMS (Mrows * Ddim)       // 4194304 per input array

typedef __bf16 bf16_t;
typedef __bf16 bf16x8 __attribute__((ext_vector_type(8)));
typedef float f32x4 __attribute__((ext_vector_type(4)));

// global->LDS DMA, 16B per lane, lds dest = wave-uniform base + lane*16
#define LOAD16_TO_LDS(g, l)                                                  \
  __builtin_amdgcn_global_load_lds(                                          \
      (const __attribute__((address_space(1))) void*)(g),                    \
      (__attribute__((address_space(3))) void*)(l), 16, 0, 0)

// ---------------------------------------------------------------------------
// Kernel 0: f32 -> bf16 conversion pre-pass (one-shot, memory-bound)
// ---------------------------------------------------------------------------
__global__ __launch_bounds__(256) void cvt_kernel(
    const float* __restrict__ o, const float* __restrict__ pos,
    const float* __restrict__ neg, bf16_t* __restrict__ ob,
    bf16_t* __restrict__ pb, bf16_t* __restrict__ nb)
{
  const int idx = blockIdx.x * 256 + threadIdx.x;   // 0 .. 3*ARR/8-1
  const int seg = idx >> 19;                        // ARR_ELEMS/8 = 2^19
  const int off = idx & ((1 << 19) - 1);
  const float* src = (seg == 0) ? o : (seg == 1) ? pos : neg;
  bf16_t* dst = (seg == 0) ? ob : (seg == 1) ? pb : nb;
  const float4 v0 = *(const float4*)(src + (size_t)off * 8);
  const float4 v1 = *(const float4*)(src + (size_t)off * 8 + 4);
  bf16x8 r = {(bf16_t)v0.x, (bf16_t)v0.y, (bf16_t)v0.z, (bf16_t)v0.w,
              (bf16_t)v1.x, (bf16_t)v1.y, (bf16_t)v1.z, (bf16_t)v1.w};
  *(bf16x8*)(dst + (size_t)off * 8) = r;
}

// ---------------------------------------------------------------------------
// Kernel 1: bf16 GEMM (o · emb^T) + partial LSE + diagonal-block extraction.
// 128x128 block, 2x2 wave grid of 64x64 wave tiles: 16 MFMA per 8
// ds_read_b128 (vs 10 for 32x128 stripes), 64-AGPR accumulator -> 4
// waves/SIMD with launch_bounds(256,4). Double-buffered LDS + DMA + XOR
// source-swizzle (0 bank conflicts, verified R4/R6).
// R5 lesson: acc[][] only ever indexed with compile-time constants.
// ---------------------------------------------------------------------------
__global__ __launch_bounds__(256, 4) void gemm_lse_kernel(
    const bf16_t* __restrict__ ob, const bf16_t* __restrict__ pb,
    const bf16_t* __restrict__ nb, float* __restrict__ pm,
    float* __restrict__ pl, float* __restrict__ blocks_raw)
{
  __shared__ bf16_t As[2][BM * BK];   // 2 x 8 KB
  __shared__ bf16_t Bs[2][BN * BK];   // 2 x 8 KB

  const int bid = blockIdx.x;
  const int rt = bid >> 6;        // 0..31
  const int cs = bid & 63;        // 0..63
  const int row0 = rt * BM;
  const bf16_t* Eb = (cs < 32) ? (pb + (size_t)cs * BN * Ddim)
                               : (nb + (size_t)(cs - 32) * BN * Ddim);

  const int t = threadIdx.x;
  const int wave = t >> 6;
  const int wr = wave & 1;        // row half (64 rows)
  const int wc = wave >> 1;       // col half (64 cols)
  const int lane = t & 63;
  const int quad = lane >> 4;
  const int l16 = lane & 15;
  const int koff = ((quad ^ ((l16 >> 1) & 3)) << 3);   // fragment chunk offset
  const int lr4 = lane >> 2;                            // staging row-in-16
  const int cstg = lane & 3;                            // staging chunk id

  f32x4 acc[4][4];
#pragma unroll
  for (int a = 0; a < 4; ++a)
#pragma unroll
    for (int b = 0; b < 4; ++b) acc[a][b] = (f32x4){0.f, 0.f, 0.f, 0.f};

  // prologue: stage tile 0 into buffer 0 (each wave stages 32 rows of A & B)
#pragma unroll
  for (int cl = 0; cl < 2; ++cl) {
    const int r = wave * 32 + cl * 16 + lr4;
    const int gc = cstg ^ ((r >> 1) & 3);
    LOAD16_TO_LDS(ob + (size_t)(row0 + r) * Ddim + gc * 8,
                  &As[0][(wave * 32 + cl * 16) * BK]);
    LOAD16_TO_LDS(Eb + (size_t)r * Ddim + gc * 8,
                  &Bs[0][(wave * 32 + cl * 16) * BK]);
  }

  int p = 0;
  for (int kc = 0; kc < KITERS; ++kc) {
    __syncthreads();   // drains DMA for buf p; protects buf p^1 reuse
    if (kc + 1 < KITERS) {
      const int k0 = (kc + 1) * BK;
#pragma unroll
      for (int cl = 0; cl < 2; ++cl) {
        const int r = wave * 32 + cl * 16 + lr4;
        const int gc = cstg ^ ((r >> 1) & 3);
        LOAD16_TO_LDS(ob + (size_t)(row0 + r) * Ddim + k0 + gc * 8,
                      &As[p ^ 1][(wave * 32 + cl * 16) * BK]);
        LOAD16_TO_LDS(Eb + (size_t)r * Ddim + k0 + gc * 8,
                      &Bs[p ^ 1][(wave * 32 + cl * 16) * BK]);
      }
    }

    bf16x8 af[4];
#pragma unroll
    for (int fm = 0; fm < 4; ++fm)
      af[fm] = *(const bf16x8*)(&As[p][(wr * 64 + fm * 16 + l16) * BK + koff]);
#pragma unroll
    for (int fn = 0; fn < 4; ++fn) {
      const bf16x8 bf = *(const bf16x8*)(&Bs[p][(wc * 64 + fn * 16 + l16) * BK + koff]);
#pragma unroll
      for (int fm = 0; fm < 4; ++fm)
        acc[fm][fn] = __builtin_amdgcn_mfma_f32_16x16x32_bf16(af[fm], bf, acc[fm][fn], 0, 0, 0);
    }
    p ^= 1;
  }

  // epilogue A: per-row (m, l) over this wave's 64 cols.
  // C/D: col = wc*64 + fn*16 + l16, row = wr*64 + fm*16 + quad*4 + r
  const int csp = cs * 2 + wc;     // partial-lse column index (0..127)
#pragma unroll
  for (int fm = 0; fm < 4; ++fm) {
#pragma unroll
    for (int r = 0; r < 4; ++r) {
      float s[4];
#pragma unroll
      for (int fn = 0; fn < 4; ++fn) s[fn] = acc[fm][fn][r] * SCALE;
      float m = fmaxf(fmaxf(s[0], s[1]), fmaxf(s[2], s[3]));
#pragma unroll
      for (int off = 1; off <= 8; off <<= 1)
        m = fmaxf(m, __shfl_xor(m, off, 64));   // row max over l16 group
      float l = 0.f;
#pragma unroll
      for (int fn = 0; fn < 4; ++fn) l += __expf(s[fn] - m);
#pragma unroll
      for (int off = 1; off <= 8; off <<= 1)
        l += __shfl_xor(l, off, 64);
      if (l16 == 0) {
        const int rg = row0 + wr * 64 + fm * 16 + quad * 4 + r;
        pm[(size_t)rg * CS + csp] = m;
        pl[(size_t)rg * CS + csp] = l;
      }
    }
  }

  // epilogue B: diagonal 16x16 sub-blocks (replaces block_dots kernel).
  // Block cs == rt covers the diagonal; waves with wr == wc hold sub-block
  // d = wr*4 + fm at fn == fm — all acc indices are compile-time constants.
  if (cs == rt && wr == wc) {
#pragma unroll
    for (int fm = 0; fm < 4; ++fm) {
      const int b = rt * 8 + wr * 4 + fm;
#pragma unroll
      for (int r = 0; r < 4; ++r)
        blocks_raw[b * 256 + (quad * 4 + r) * 16 + l16] = acc[fm][fm][r] * SCALE;
    }
  }
}

// ---------------------------------------------------------------------------
// Kernel 2: fused lse-combine + lane-parallel JV LAP + atomic loss.
// Single wave per block, no barriers; u[] in row-lane registers.
// ---------------------------------------------------------------------------
__global__ __launch_bounds__(64) void hungarian_kernel(
    const float* __restrict__ blocks_raw, const float* __restrict__ pm,
    const float* __restrict__ pl, float* __restrict__ out)
{
  const int b = blockIdx.x;
  const int L = threadIdx.x;
  __shared__ float C[16][16];
  __shared__ float lse_s[16];

  for (int e = L; e < 256; e += 64)
    C[e >> 4][e & 15] = blocks_raw[b * 256 + e];

  // combine 128 partial (m,l) per row -> lse. lane = r + 16*g handles
  // partial chunk [g*32, g*32+32) of row r, then merges across g.
  {
    const int r = L & 15, g = L >> 4;
    const size_t base = (size_t)(b * 16 + r) * CS + g * 32;
    float m = -INFINITY, l = 0.f;
#pragma unroll
    for (int k = 0; k < 32; ++k) {
      const float m2 = pm[base + k];
      const float l2 = pl[base + k];
      const float M = fmaxf(m, m2);
      l = l * __expf(m - M) + l2 * __expf(m2 - M);
      m = M;
    }
#pragma unroll
    for (int off = 16; off <= 32; off <<= 1) {
      const float m2 = __shfl_xor(m, off, 64);
      const float l2 = __shfl_xor(l, off, 64);
      const float M = fmaxf(m, m2);
      l = l * __expf(m - M) + l2 * __expf(m2 - M);
      m = M;
    }
    if (g == 0) lse_s[r] = m + logf(l);
  }

  const float INF = 3.0e38f;
  float vj = 0.f, u_reg = 0.f;
  int pj = 0;
  float minv = INF;
  int wayj = 0;
  bool usedj = false, on_tree = false;

  for (int i = 1; i <= 16; ++i) {
    if (L == 0) pj = i;          // p[0] = current row
    minv = INF; wayj = 0; usedj = false; on_tree = false;
    int j0 = 0;
    while (true) {
      usedj = usedj || (L == j0);
      const int i0 = __shfl(pj, j0, 64);        // row entering the tree
      if (L == i0) on_tree = true;
      const float ui0 = __shfl(u_reg, i0, 64);
      if (L >= 1 && L <= 16 && !usedj) {
        const float cur = -C[i0 - 1][L - 1] - ui0 - vj;
        if (cur < minv) { minv = cur; wayj = j0; }
      }
      float cand = (L >= 1 && L <= 16 && !usedj) ? minv : INF;
      int idx = L;
#pragma unroll
      for (int off = 16; off > 0; off >>= 1) {
        const float ov = __shfl_xor(cand, off, 32);
        const int oi = __shfl_xor(idx, off, 32);
        if (ov < cand || (ov == cand && oi < idx)) { cand = ov; idx = oi; }
      }
      const float delta = cand;                  // valid in lanes 0..31
      const int j1 = __builtin_amdgcn_readfirstlane(idx);  // uniform
      if (L >= 1 && L <= 16) {
        if (usedj) vj -= delta; else minv -= delta;
        if (on_tree) u_reg += delta;
      }
      j0 = j1;
      const int pj0 = __shfl(pj, j0, 64);
      if (pj0 == 0) break;
    }
    // augment
    while (j0 != 0) {
      const int j1a = __shfl(wayj, j0, 64);
      const int pjn = __shfl(pj, j1a, 64);
      if (L == j0) pj = pjn;
      j0 = j1a;
    }
  }

  float loss = 0.f;
  if (L >= 1 && L <= 16) loss = lse_s[pj - 1] - C[pj - 1][L - 1];
#pragma unroll
  for (int off = 32; off > 0; off >>= 1) loss += __shfl_down(loss, off, 64);
  if (L == 0) atomicAdd(out, loss * (1.0f / 4096.0f));
}

extern "C" void kernel_launch(void* const* d_in, const int* in_sizes, int n_in,
                              void* d_out, int out_size, void* d_ws, size_t ws_size,
                              hipStream_t stream) {
  const float* o   = (const float*)d_in[0];  // (256,16,1024) f32
  const float* pos = (const float*)d_in[1];
  const float* neg = (const float*)d_in[2];
  float* out = (float*)d_out;

  float* ws = (float*)d_ws;
  float* pm         = ws;                       // 4096*128 = 2 MB
  float* pl         = pm + (size_t)4096 * CS;   // 4096*128 = 2 MB
  float* blocks_raw = pl + (size_t)4096 * CS;   // 256*256
  bf16_t* ob = (bf16_t*)(blocks_raw + 65536);   // 3 x 4194304 bf16
  bf16_t* pb = ob + (size_t)ARR_ELEMS;
  bf16_t* nb = pb + (size_t)ARR_ELEMS;

  hipMemsetAsync(out, 0, sizeof(float), stream);
  cvt_kernel<<<3 * ARR_ELEMS / 8 / 256, 256, 0, stream>>>(o, pos, neg, ob, pb, nb);
  gemm_lse_kernel<<<RT * NCS, 256, 0, stream>>>(ob, pb, nb, pm, pl, blocks_raw);
  hungarian_kernel<<<256, 64, 0, stream>>>(blocks_raw, pm, pl, out);
}